// Round 1
// baseline (860.911 us; speedup 1.0000x reference)
//
#include <hip/hip_runtime.h>
#include <stdint.h>

#define NT 256
#define ROWLEN 8192
#define EPT (ROWLEN / NT)   // 32 elements per thread per input
#define NV4 (EPT / 4)       // 8 float4 loads per input per thread

// ---- monotonic float <-> uint32 key mapping (order preserving) ----
__device__ __forceinline__ uint32_t f2key(float f) {
    uint32_t u = __float_as_uint(f);
    return (u & 0x80000000u) ? ~u : (u | 0x80000000u);
}
__device__ __forceinline__ float key2f(uint32_t k) {
    uint32_t u = (k & 0x80000000u) ? (k & 0x7fffffffu) : ~k;
    return __uint_as_float(u);
}

// unpack two u64s of 8-bit counters (bins 0..7 in lo, 8..15 in hi)
// into 8 u32 words of two 16-bit counters each: w[i] = {bin 2i (lo16), bin 2i+1 (hi16)}
__device__ __forceinline__ void unpack8(uint64_t lo, uint64_t hi, uint32_t w[8]) {
    uint32_t x;
    x = (uint32_t)lo;
    w[0] = (x & 0xFFu) | ((x & 0xFF00u) << 8);
    w[1] = ((x >> 16) & 0xFFu) | ((x >> 24) << 16);
    x = (uint32_t)(lo >> 32);
    w[2] = (x & 0xFFu) | ((x & 0xFF00u) << 8);
    w[3] = ((x >> 16) & 0xFFu) | ((x >> 24) << 16);
    x = (uint32_t)hi;
    w[4] = (x & 0xFFu) | ((x & 0xFF00u) << 8);
    w[5] = ((x >> 16) & 0xFFu) | ((x >> 24) << 16);
    x = (uint32_t)(hi >> 32);
    w[6] = (x & 0xFFu) | ((x & 0xFF00u) << 8);
    w[7] = ((x >> 16) & 0xFFu) | ((x >> 24) << 16);
}

__global__ __launch_bounds__(NT, 2) void combine_kernel(
    const float* __restrict__ A, const float* __restrict__ B,
    const int* __restrict__ thr, float* __restrict__ C)
{
    // 16 bins packed as 8 u32 (two 16-bit counts each), double-buffered per round parity
    __shared__ uint32_t binsA[2][8];
    __shared__ uint32_t binsB[2][8];
    __shared__ uint32_t bcast[4];   // prefA, remA, prefB, remB

    const int row  = blockIdx.x;
    const int tid  = threadIdx.x;
    const int lane = tid & 63;

    const float4* A4 = (const float4*)(A + (size_t)row * ROWLEN);
    const float4* B4 = (const float4*)(B + (size_t)row * ROWLEN);

    // ---- load whole row into registers, convert to monotonic keys ----
    uint32_t ka[EPT], kb[EPT];
    {
        float4 va[NV4], vb[NV4];
#pragma unroll
        for (int j = 0; j < NV4; ++j) va[j] = A4[tid + j * NT];
#pragma unroll
        for (int j = 0; j < NV4; ++j) vb[j] = B4[tid + j * NT];
#pragma unroll
        for (int j = 0; j < NV4; ++j) {
            ka[4*j+0] = f2key(va[j].x); ka[4*j+1] = f2key(va[j].y);
            ka[4*j+2] = f2key(va[j].z); ka[4*j+3] = f2key(va[j].w);
            kb[4*j+0] = f2key(vb[j].x); kb[4*j+1] = f2key(vb[j].y);
            kb[4*j+2] = f2key(vb[j].z); kb[4*j+3] = f2key(vb[j].w);
        }
    }

    if (tid < 8) {
        binsA[0][tid] = 0; binsA[1][tid] = 0;
        binsB[0][tid] = 0; binsB[1][tid] = 0;
    }
    if (tid == 0) {
        uint32_t kth = (uint32_t)thr[0];
        bcast[0] = 0; bcast[1] = kth;   // A: prefix, remaining rank
        bcast[2] = 0; bcast[3] = kth;   // B
    }
    __syncthreads();

    // ================= round 0 (all elements active, top nibble) =================
    {
        uint64_t loA = 0, hiA = 0, loB = 0, hiB = 0;
#pragma unroll
        for (int j = 0; j < EPT; ++j) {
            uint32_t d = ka[j] >> 28;
            uint64_t w = 1ull << ((d & 7u) << 3);
            if (d & 8u) hiA += w; else loA += w;
            d = kb[j] >> 28;
            w = 1ull << ((d & 7u) << 3);
            if (d & 8u) hiB += w; else loB += w;
        }
        uint32_t wA[8], wB[8];
        unpack8(loA, hiA, wA);
        unpack8(loB, hiB, wB);
        // wave reduce (16-bit fields: wave max 64*32 = 2048, safe)
#pragma unroll
        for (int s = 1; s < 64; s <<= 1) {
#pragma unroll
            for (int i = 0; i < 8; ++i) {
                wA[i] += __shfl_xor(wA[i], s, 64);
                wB[i] += __shfl_xor(wB[i], s, 64);
            }
        }
        if (lane == 0) {
#pragma unroll
            for (int i = 0; i < 8; ++i) {
                atomicAdd(&binsA[0][i], wA[i]);
                atomicAdd(&binsB[0][i], wB[i]);
            }
        }
    }
    __syncthreads();
    // selection for round 0 (thread 0 -> A, thread 64 -> B, concurrent waves)
    if (tid == 0 || tid == 64) {
        const int inb = tid >> 6;
        uint32_t* bins = inb ? binsB[0] : binsA[0];
        uint32_t pref = bcast[inb * 2 + 0];
        uint32_t rem  = bcast[inb * 2 + 1];
        uint32_t dsel = 0;
#pragma unroll 1
        for (int d = 15; d >= 0; --d) {
            uint32_t c = (bins[d >> 1] >> ((d & 1) << 4)) & 0xFFFFu;
            if (rem < c) { dsel = (uint32_t)d; break; }
            rem -= c;
        }
        bcast[inb * 2 + 0] = (pref << 4) | dsel;
        bcast[inb * 2 + 1] = rem;
    }
    // (bins[1] already zero from init; nothing to zero for round 1)
    __syncthreads();

    // ================= rounds 1..7 (sparse; ballot-skip inactive slots) =========
#pragma unroll 1
    for (int r = 1; r < 8; ++r) {
        const int shift = 28 - 4 * r;
        const int sh4   = shift + 4;
        const int cur   = r & 1;
        const int nxt   = cur ^ 1;
        const uint32_t pA = bcast[0];
        const uint32_t pB = bcast[2];

        uint64_t loA = 0, hiA = 0, loB = 0, hiB = 0;
#pragma unroll
        for (int j = 0; j < EPT; ++j) {
            {
                uint32_t k = ka[j];
                bool act = (k >> sh4) == pA;
                if (__ballot(act)) {
                    uint32_t d = (k >> shift) & 15u;
                    uint64_t w = act ? (1ull << ((d & 7u) << 3)) : 0ull;
                    if (d & 8u) hiA += w; else loA += w;
                }
            }
            {
                uint32_t k = kb[j];
                bool act = (k >> sh4) == pB;
                if (__ballot(act)) {
                    uint32_t d = (k >> shift) & 15u;
                    uint64_t w = act ? (1ull << ((d & 7u) << 3)) : 0ull;
                    if (d & 8u) hiB += w; else loB += w;
                }
            }
        }
        // sparse atomic accumulation (few nonzero words in tail rounds)
        if (loA | hiA) {
            uint32_t w[8]; unpack8(loA, hiA, w);
#pragma unroll
            for (int i = 0; i < 8; ++i) if (w[i]) atomicAdd(&binsA[cur][i], w[i]);
        }
        if (loB | hiB) {
            uint32_t w[8]; unpack8(loB, hiB, w);
#pragma unroll
            for (int i = 0; i < 8; ++i) if (w[i]) atomicAdd(&binsB[cur][i], w[i]);
        }
        __syncthreads();

        if (tid == 0 || tid == 64) {
            const int inb = tid >> 6;
            uint32_t* bins = inb ? binsB[cur] : binsA[cur];
            uint32_t pref = bcast[inb * 2 + 0];
            uint32_t rem  = bcast[inb * 2 + 1];
            uint32_t dsel = 0;
#pragma unroll 1
            for (int d = 15; d >= 0; --d) {
                uint32_t c = (bins[d >> 1] >> ((d & 1) << 4)) & 0xFFFFu;
                if (rem < c) { dsel = (uint32_t)d; break; }
                rem -= c;
            }
            bcast[inb * 2 + 0] = (pref << 4) | dsel;
            bcast[inb * 2 + 1] = rem;
        }
        // zero the buffer last used in round r-1; it is needed (zeroed) by round r+1
        if (tid >= 128 && tid < 136) {
            binsA[nxt][tid - 128] = 0;
            binsB[nxt][tid - 128] = 0;
        }
        __syncthreads();
    }

    // ================= epilogue: mask + combine, all from registers =============
    const uint32_t keyA = bcast[0];
    const uint32_t keyB = bcast[2];
    const uint32_t kmax = keyA > keyB ? keyA : keyB;
    const float mv = key2f(kmax);

    float4* C4 = (float4*)(C + (size_t)row * ROWLEN);
#pragma unroll
    for (int j = 0; j < NV4; ++j) {
        float a0 = key2f(ka[4*j+0]), b0 = key2f(kb[4*j+0]);
        float a1 = key2f(ka[4*j+1]), b1 = key2f(kb[4*j+1]);
        float a2 = key2f(ka[4*j+2]), b2 = key2f(kb[4*j+2]);
        float a3 = key2f(ka[4*j+3]), b3 = key2f(kb[4*j+3]);
        float4 o;
        o.x = (a0 <= mv || b0 <= mv) ? a0 * b0 : a0 + b0;
        o.y = (a1 <= mv || b1 <= mv) ? a1 * b1 : a1 + b1;
        o.z = (a2 <= mv || b2 <= mv) ? a2 * b2 : a2 + b2;
        o.w = (a3 <= mv || b3 <= mv) ? a3 * b3 : a3 + b3;
        C4[tid + j * NT] = o;
    }
}

extern "C" void kernel_launch(void* const* d_in, const int* in_sizes, int n_in,
                              void* d_out, int out_size, void* d_ws, size_t ws_size,
                              hipStream_t stream) {
    const float* A  = (const float*)d_in[0];
    const float* Bm = (const float*)d_in[1];
    const int* thr  = (const int*)d_in[2];
    float* C = (float*)d_out;
    const int rows = in_sizes[0] / ROWLEN;   // 4*2048 = 8192
    hipLaunchKernelGGL(combine_kernel, dim3(rows), dim3(NT), 0, stream, A, Bm, thr, C);
}